// Round 11
// baseline (289.325 us; speedup 1.0000x reference)
//
#include <hip/hip_runtime.h>
#include <math.h>

#define DIN 3072
#define DF 640
#define MROWS 400
#define QROWS 240
#define NMAT 400
#define PN 416          // padded A dim (13*32, 26*16)
#define NRHS 16
#define CREG 50.0f
#define PVSTEPS 5
#define CSTEPS 25       // Chebyshev: 2*q^25 ~ 3.5e-3 rel (q~0.78)
#define KSPLIT 4        // feat split-K factor
#define GBLK 13         // solve blocks; each owns 32 cols of A in LDS
#define SCOLS 32
#define SPAD 40         // solve LDS pad (R9-proven)
#define FPAD 72         // feat staging pad
#define MTILES 28       // M = FX@K^T: 4 row-tiles x 7 col-tiles of 64

typedef __attribute__((ext_vector_type(8))) short bf8v;   // 8 bf16 (4 VGPRs)
typedef __attribute__((ext_vector_type(4))) short s4v;    // 4 bf16 (8 B)
typedef __attribute__((ext_vector_type(4))) float f32x4;  // MFMA acc

__device__ __forceinline__ short bf16_rn(float x) {
  unsigned u = __float_as_uint(x);
  u += 0x7FFFu + ((u >> 16) & 1u);
  return (short)(u >> 16);
}
__device__ __forceinline__ void split_sh(float x, short& h, short& l) {
  h = bf16_rn(x);
  float hf = __uint_as_float(((unsigned)(unsigned short)h) << 16);
  l = bf16_rn(x - hf);
}
__device__ __forceinline__ float bf2f(short h) {
  return __uint_as_float(((unsigned)(unsigned short)h) << 16);
}

// ---- feat split-K: [S;Q](640x3072) @ Wb -> 4 partial slices (atomic-free) -
__global__ __launch_bounds__(256) void gemm_feat_sk(const float* __restrict__ S,
                                                    const float* __restrict__ Qm,
                                                    const float* __restrict__ Wb,
                                                    float* __restrict__ Acc) {
  __shared__ short Ash[64][FPAD];
  __shared__ short Asl[64][FPAD];
  __shared__ short Bsh[64][FPAD];
  __shared__ short Bsl[64][FPAD];
  int tid = threadIdx.x;
  int wave = tid >> 6, lane = tid & 63, l16 = lane & 15, quad = lane >> 4;
  int by = blockIdx.y, bx = blockIdx.x, bz = blockIdx.z;
  int colBase = bx * 64;
  int kbeg = bz * (DIN / KSPLIT), kend = kbeg + (DIN / KSPLIT);
  f32x4 acc[4] = {{0,0,0,0},{0,0,0,0},{0,0,0,0},{0,0,0,0}};
  for (int k0 = kbeg; k0 < kend; k0 += 64) {
    __syncthreads();
#pragma unroll
    for (int p = 0; p < 4; ++p) {
      int cid = tid + 256 * p;            // 0..1023
      int row = cid >> 4, kc4 = (cid & 15) * 4;
      int arow = by * 64 + row;
      const float* sr = (arow < MROWS) ? (S + (size_t)arow * DIN)
                                       : (Qm + (size_t)(arow - MROWS) * DIN);
      float4 v = *reinterpret_cast<const float4*>(sr + k0 + kc4);
      s4v hv, lv;
      short h, l;
      split_sh(v.x, h, l); hv[0] = h; lv[0] = l;
      split_sh(v.y, h, l); hv[1] = h; lv[1] = l;
      split_sh(v.z, h, l); hv[2] = h; lv[2] = l;
      split_sh(v.w, h, l); hv[3] = h; lv[3] = l;
      *reinterpret_cast<s4v*>(&Ash[row][kc4]) = hv;
      *reinterpret_cast<s4v*>(&Asl[row][kc4]) = lv;
    }
#pragma unroll
    for (int p = 0; p < 4; ++p) {
      int cid = tid + 256 * p;
      int r = cid >> 4, c4 = (cid & 15) * 4;
      float4 w = *reinterpret_cast<const float4*>(Wb + (size_t)(k0 + r) * DF + colBase + c4);
      short h, l;
      split_sh(w.x, h, l); Bsh[c4 + 0][r] = h; Bsl[c4 + 0][r] = l;
      split_sh(w.y, h, l); Bsh[c4 + 1][r] = h; Bsl[c4 + 1][r] = l;
      split_sh(w.z, h, l); Bsh[c4 + 2][r] = h; Bsl[c4 + 2][r] = l;
      split_sh(w.w, h, l); Bsh[c4 + 3][r] = h; Bsl[c4 + 3][r] = l;
    }
    __syncthreads();
#pragma unroll
    for (int kk = 0; kk < 64; kk += 32) {
      int ko = kk + quad * 8;
      bf8v ah = *reinterpret_cast<const bf8v*>(&Ash[wave * 16 + l16][ko]);
      bf8v al = *reinterpret_cast<const bf8v*>(&Asl[wave * 16 + l16][ko]);
#pragma unroll
      for (int t = 0; t < 4; ++t) {
        bf8v bh = *reinterpret_cast<const bf8v*>(&Bsh[t * 16 + l16][ko]);
        bf8v bl = *reinterpret_cast<const bf8v*>(&Bsl[t * 16 + l16][ko]);
        acc[t] = __builtin_amdgcn_mfma_f32_16x16x32_bf16(ah, bh, acc[t], 0, 0, 0);
        acc[t] = __builtin_amdgcn_mfma_f32_16x16x32_bf16(ah, bl, acc[t], 0, 0, 0);
        acc[t] = __builtin_amdgcn_mfma_f32_16x16x32_bf16(al, bh, acc[t], 0, 0, 0);
      }
    }
  }
  float* Ap = Acc + (size_t)bz * 640 * DF;
  int row0 = by * 64 + wave * 16;
#pragma unroll
  for (int t = 0; t < 4; ++t)
#pragma unroll
    for (int r = 0; r < 4; ++r) {
      int row = row0 + quad * 4 + r;
      int col = colBase + t * 16 + l16;
      Ap[(size_t)row * DF + col] = acc[t][r];
    }
}

// ---- reduce 4 partial slices -> Kh/Kl (rows<400) / FX; block 0 zeroes ctrl
__global__ __launch_bounds__(256) void feat_reduce(const float* __restrict__ Acc,
                                                   short* __restrict__ Kh,
                                                   short* __restrict__ Kl,
                                                   float* __restrict__ FX,
                                                   float* __restrict__ zbuf) {
  int tid = threadIdx.x;
  if (blockIdx.x == 0) {
    for (int e = tid; e < 14160; e += 256) zbuf[e] = 0.f;
  }
  int idx = blockIdx.x * 256 + tid;   // < 640*640
  if (idx >= 640 * DF) return;
  float v = Acc[idx] + Acc[idx + 409600] + Acc[idx + 819200] + Acc[idx + 1228800];
  int row = idx / DF, col = idx - row * DF;
  if (row < MROWS) {
    short h, l; split_sh(v, h, l);
    Kh[(size_t)row * DF + col] = h;
    Kl[(size_t)row * DF + col] = l;
  } else {
    FX[(size_t)(row - MROWS) * DF + col] = v;
  }
}

// ---- fused: blocks 0..12 = 32-column-split Chebyshev solve (builds its own
//      A^T slice from Kh/Kl via MFMA — gemm_aul is fused & deleted);
//      blocks 13..40 = M = FX @ K^T (hides under the solve). -----------------
__global__ __launch_bounds__(256) void solve_and_m(const float* __restrict__ FX,
                                                   const short* __restrict__ Kh,
                                                   const short* __restrict__ Kl,
                                                   float* __restrict__ Y0,
                                                   float* __restrict__ Y1,
                                                   float* __restrict__ V0,
                                                   float* __restrict__ V1,
                                                   float* __restrict__ rq,
                                                   unsigned* __restrict__ bar,
                                                   float* __restrict__ X,
                                                   float* __restrict__ M) {
  int tid = threadIdx.x, b = blockIdx.x;
  int wave = tid >> 6, lane = tid & 63, l16 = lane & 15, quad = lane >> 4;
  const bf8v bzero = {0,0,0,0,0,0,0,0};

  if (b >= GBLK) {
    // ================= M role: tile of FX(240x640) @ K^T(640x400) =========
    int mt = b - GBLK;             // 0..27
    int mb = mt / 7, nb = mt - (mt / 7) * 7;
    int q0 = mb * 64 + wave * 16;
    f32x4 acc[4] = {{0,0,0,0},{0,0,0,0},{0,0,0,0},{0,0,0,0}};
    int arow = q0 + l16;
    bool aOk = (arow < QROWS);
    const float* fr = FX + (size_t)(aOk ? arow : 0) * DF;
    for (int k0 = 0; k0 < DF; k0 += 32) {
      int ka = k0 + quad * 8;
      bf8v ah = bzero, al = bzero;
      if (aOk) {
        float4 a0 = *reinterpret_cast<const float4*>(fr + ka);
        float4 a1 = *reinterpret_cast<const float4*>(fr + ka + 4);
        float av[8] = {a0.x, a0.y, a0.z, a0.w, a1.x, a1.y, a1.z, a1.w};
#pragma unroll
        for (int j = 0; j < 8; ++j) { short h, l; split_sh(av[j], h, l); ah[j] = h; al[j] = l; }
      }
#pragma unroll
      for (int t = 0; t < 4; ++t) {
        int n = nb * 64 + t * 16 + l16;
        bf8v bh = bzero, bl = bzero;
        if (n < NMAT) {
          bh = *reinterpret_cast<const bf8v*>(Kh + (size_t)n * DF + ka);
          bl = *reinterpret_cast<const bf8v*>(Kl + (size_t)n * DF + ka);
        }
        acc[t] = __builtin_amdgcn_mfma_f32_16x16x32_bf16(ah, bh, acc[t], 0, 0, 0);
        acc[t] = __builtin_amdgcn_mfma_f32_16x16x32_bf16(ah, bl, acc[t], 0, 0, 0);
        acc[t] = __builtin_amdgcn_mfma_f32_16x16x32_bf16(al, bh, acc[t], 0, 0, 0);
      }
    }
#pragma unroll
    for (int t = 0; t < 4; ++t)
#pragma unroll
      for (int r = 0; r < 4; ++r) {
        int row = q0 + quad * 4 + r;
        int col = nb * 64 + t * 16 + l16;
        if (row < QROWS && col < NMAT) M[(size_t)row * NMAT + col] = acc[t][r];
      }
    return;
  }

  // ================= solve role: 32-column slice ===========================
  __shared__ short AsT_h[PN][SPAD];   // AsT[i][jl] = A[r0+jl][i] (sym) 33.3KB
  __shared__ short AsT_l[PN][SPAD];   // 33.3KB
  __shared__ short dbT_h[16][SPAD];   // d B-operand [c][k_local]
  __shared__ short dbT_l[16][SPAD];
  __shared__ float pvp[SCOLS], pvc[SCOLS];
  __shared__ float scal[2];
  int r0 = b * SCOLS;

  // ---- build own A^T slice: A[r0+jl][i] = Kown . Kall^T (+CREG diag) ----
  {
    f32x4 accA[2][7];
#pragma unroll
    for (int mt = 0; mt < 2; ++mt)
#pragma unroll
      for (int ti = 0; ti < 7; ++ti) accA[mt][ti] = (f32x4){0,0,0,0};
    for (int k0 = 0; k0 < DF; k0 += 32) {
      int ka = k0 + quad * 8;
      bf8v ahh[2], all2[2];
#pragma unroll
      for (int mt = 0; mt < 2; ++mt) {
        int arow = r0 + mt * 16 + l16;
        bool aOk = (arow < MROWS);
        ahh[mt]  = aOk ? *reinterpret_cast<const bf8v*>(Kh + (size_t)arow * DF + ka) : bzero;
        all2[mt] = aOk ? *reinterpret_cast<const bf8v*>(Kl + (size_t)arow * DF + ka) : bzero;
      }
      int ti = 0;
      for (int t = wave; t < 26; t += 4, ++ti) {
        int iCol = t * 16 + l16;
        bool bOk = (iCol < MROWS);
        bf8v bh = bOk ? *reinterpret_cast<const bf8v*>(Kh + (size_t)iCol * DF + ka) : bzero;
        bf8v bl = bOk ? *reinterpret_cast<const bf8v*>(Kl + (size_t)iCol * DF + ka) : bzero;
#pragma unroll
        for (int mt = 0; mt < 2; ++mt) {
          accA[mt][ti] = __builtin_amdgcn_mfma_f32_16x16x32_bf16(ahh[mt], bh, accA[mt][ti], 0, 0, 0);
          accA[mt][ti] = __builtin_amdgcn_mfma_f32_16x16x32_bf16(ahh[mt], bl, accA[mt][ti], 0, 0, 0);
          accA[mt][ti] = __builtin_amdgcn_mfma_f32_16x16x32_bf16(all2[mt], bh, accA[mt][ti], 0, 0, 0);
        }
      }
    }
    // scatter C/D (col=lane&15 -> i, row=quad*4+r -> jl) into AsT bf16 pair
    int ti = 0;
    for (int t = wave; t < 26; t += 4, ++ti) {
      int i = t * 16 + l16;
#pragma unroll
      for (int mt = 0; mt < 2; ++mt)
#pragma unroll
        for (int r = 0; r < 4; ++r) {
          int jl = mt * 16 + quad * 4 + r;
          float v = accA[mt][ti][r];
          if (r0 + jl == i && i < MROWS) v += CREG;
          short h, l; split_sh(v, h, l);
          AsT_h[i][jl] = h; AsT_l[i][jl] = l;
        }
    }
  }
  for (int e = tid; e < 16 * SPAD; e += 256) {
    (&dbT_h[0][0])[e] = 0; (&dbT_l[0][0])[e] = 0;
  }
  __syncthreads();
  if (tid < SCOLS) {
    int gi = r0 + tid;
    float v = (gi < NMAT) ? (1.f + 0.125f * (float)(gi & 7)) : 0.f;
    pvc[tid] = v; pvp[tid] = 0.f;
    dbT_h[0][tid] = bf16_rn(v);
  }
  __syncthreads();

  unsigned ph = 0;
  auto gridbar = [&]() {
    __syncthreads();
    ++ph;
    if (tid == 0) {
      unsigned tgt = ph * GBLK;
      __hip_atomic_fetch_add(bar, 1u, __ATOMIC_RELEASE, __HIP_MEMORY_SCOPE_AGENT);
      while (__hip_atomic_load(bar, __ATOMIC_RELAXED, __HIP_MEMORY_SCOPE_AGENT) < tgt)
        __builtin_amdgcn_s_sleep(2);
    }
    __syncthreads();
  };

  // ---- power iteration: partial y = A[:,own] @ v_own, hi only, col 0 ----
  for (int s = 0; s < PVSTEPS; ++s) {
    float* Yv = (s & 1) ? V1 : V0;
    for (int t = wave; t < 26; t += 4) {
      f32x4 acc = {0, 0, 0, 0};
      bf8v bh = *reinterpret_cast<const bf8v*>(&dbT_h[l16][quad * 8]);
      bf8v ah = *reinterpret_cast<const bf8v*>(&AsT_h[t * 16 + l16][quad * 8]);
      acc = __builtin_amdgcn_mfma_f32_16x16x32_bf16(ah, bh, acc, 0, 0, 0);
      if (l16 == 0) {
#pragma unroll
        for (int r_ = 0; r_ < 4; ++r_)
          atomicAdd(&Yv[t * 16 + quad * 4 + r_], acc[r_]);
      }
    }
    gridbar();
    if (tid < SCOLS) {
      float y = atomicExch(&Yv[r0 + tid], 0.f);   // coherent read + re-zero
      float v = y * (1.f / 4096.f);
      pvp[tid] = pvc[tid];
      pvc[tid] = v;
      dbT_h[0][tid] = bf16_rn(v);
    }
    __syncthreads();
  }
  // ---- Rayleigh quotient (partial dots over own slice) ----
  if (tid == 0) {
    float n = 0.f, dd = 0.f;
    for (int u = 0; u < SCOLS; ++u) { n += pvp[u] * pvc[u]; dd += pvp[u] * pvp[u]; }
    atomicAdd(&rq[0], n);
    atomicAdd(&rq[1], dd);
  }
  gridbar();
  if (tid == 0) {
    float rn = atomicAdd(&rq[0], 0.f), rd = atomicAdd(&rq[1], 0.f);
    float rqv = 4096.f * rn / rd;
    float bb = 1.3f * rqv;
    if (!(bb > 800.f)) bb = 12000.f;   // degenerate/NaN fallback
    if (bb > 100000.f) bb = 100000.f;
    scal[0] = 0.5f * (bb + CREG);      // theta
    scal[1] = 0.5f * (bb - CREG);      // delta
  }
  __syncthreads();
  float theta = scal[0], delta = scal[1];
  float sigma = theta / delta, rho = 1.f / sigma;

  // ---- Chebyshev init: thread owns 2 (rl, c) pairs; overwrites PV d ----
  float xr[2], rr[2], dr[2];
#pragma unroll
  for (int m = 0; m < 2; ++m) {
    int rl = (tid >> 4) + 16 * m, c = tid & 15, gi = r0 + rl;
    float pc = (gi < NMAT && (gi / 25) == c) ? 1.f : 0.f;
    xr[m] = 0.f; rr[m] = pc; dr[m] = pc / theta;
    short h, l; split_sh(dr[m], h, l);
    dbT_h[c][rl] = h; dbT_l[c][rl] = l;
  }
  __syncthreads();

  // ---- Chebyshev steps (Saad Alg 12.1); CSTEPS-1 matvecs + final add ----
  for (int k = 0; k < CSTEPS - 1; ++k) {
    float* Yv = (k & 1) ? Y1 : Y0;
    for (int t = wave; t < 26; t += 4) {
      f32x4 acc = {0, 0, 0, 0};
      bf8v bh = *reinterpret_cast<const bf8v*>(&dbT_h[l16][quad * 8]);
      bf8v bl = *reinterpret_cast<const bf8v*>(&dbT_l[l16][quad * 8]);
      bf8v ah = *reinterpret_cast<const bf8v*>(&AsT_h[t * 16 + l16][quad * 8]);
      bf8v al = *reinterpret_cast<const bf8v*>(&AsT_l[t * 16 + l16][quad * 8]);
      acc = __builtin_amdgcn_mfma_f32_16x16x32_bf16(ah, bh, acc, 0, 0, 0);
      acc = __builtin_amdgcn_mfma_f32_16x16x32_bf16(ah, bl, acc, 0, 0, 0);
      acc = __builtin_amdgcn_mfma_f32_16x16x32_bf16(al, bh, acc, 0, 0, 0);
#pragma unroll
      for (int r_ = 0; r_ < 4; ++r_)
        atomicAdd(&Yv[(t * 16 + quad * 4 + r_) * 16 + l16], acc[r_]);
    }
    gridbar();
    float rho1 = 1.f / (2.f * sigma - rho);
    float s1 = rho1 * rho, s2 = 2.f * rho1 / delta;
    rho = rho1;
#pragma unroll
    for (int m = 0; m < 2; ++m) {
      int rl = (tid >> 4) + 16 * m, c = tid & 15, gi = r0 + rl;
      float mv = atomicExch(&Yv[gi * 16 + c], 0.f);   // read + re-zero
      xr[m] += dr[m];
      rr[m] -= mv;
      float dn = s1 * dr[m] + s2 * rr[m];
      dr[m] = dn;
      short h, l; split_sh(dn, h, l);
      dbT_h[c][rl] = h; dbT_l[c][rl] = l;
    }
    __syncthreads();
  }
#pragma unroll
  for (int m = 0; m < 2; ++m) {
    int rl = (tid >> 4) + 16 * m, c = tid & 15, gi = r0 + rl;
    if (gi < NMAT) X[gi * NRHS + c] = xr[m] + dr[m];
  }
}

// ---- logits[q][c] = -gamma * sum_i M[q][i] X[i][c]  (tiny, 240x400x16) ----
__global__ __launch_bounds__(256) void logits_kernel(const float* __restrict__ M,
                                                     const float* __restrict__ X,
                                                     const float* __restrict__ gamma,
                                                     float* __restrict__ out) {
  __shared__ float Xs[NMAT * NRHS];     // 25.6 KB
  __shared__ float Ms[16][NMAT];        // 25.6 KB
  int tid = threadIdx.x;
  int q0 = blockIdx.x * 16;
  for (int e = tid; e < NMAT * NRHS; e += 256) Xs[e] = X[e];
  for (int e = tid; e < 16 * NMAT; e += 256) {
    int rl = e / NMAT, i = e - (e / NMAT) * NMAT;
    Ms[rl][i] = M[(size_t)(q0 + rl) * NMAT + i];
  }
  __syncthreads();
  int ql = tid >> 4, c = tid & 15;
  float acc = 0.f;
  for (int i = 0; i < NMAT; ++i) acc += Ms[ql][i] * Xs[i * NRHS + c];
  out[(size_t)(q0 + ql) * NRHS + c] = -gamma[0] * acc;
}

extern "C" void kernel_launch(void* const* d_in, const int* in_sizes, int n_in,
                              void* d_out, int out_size, void* d_ws, size_t ws_size,
                              hipStream_t stream) {
  const float* S = (const float*)d_in[0];
  const float* Qm = (const float*)d_in[1];
  const float* Wb = (const float*)d_in[2];
  const float* gamma = (const float*)d_in[3];
  float* out = (float*)d_out;
  char* base = (char*)d_ws;
  short* Kh   = (short*)(base);                  // 400*640*2 = 512,000
  short* Kl   = (short*)(base + 512000);         // 512,000
  float* FX   = (float*)(base + 1024000);        // 240*640*4 = 614,400
  float* Mm   = (float*)(base + 1638400);        // 240*400*4 = 384,000
  float* Xb   = (float*)(base + 2022400);        // 25,600
  unsigned* bar = (unsigned*)(base + 2048000);   // ctrl (64 B): bar, rq
  float* rq   = (float*)(base + 2048008);
  float* zbuf = (float*)(base + 2048000);        // zero region: ctrl..V1 (14160 f)
  float* Y0   = (float*)(base + 2048064);        // 26,624
  float* Y1   = (float*)(base + 2074688);        // 26,624
  float* V0   = (float*)(base + 2101312);        // 1,664
  float* V1   = (float*)(base + 2102976);        // 1,664 -> end 2,104,640
  float* Acc  = (float*)(base + 2104640);        // 4*640*640*4 = 6,553,600
                                                 // -> total 8,658,240 B

  gemm_feat_sk<<<dim3(10, 10, KSPLIT), 256, 0, stream>>>(S, Qm, Wb, Acc);
  feat_reduce<<<1600, 256, 0, stream>>>(Acc, Kh, Kl, FX, zbuf);
  solve_and_m<<<GBLK + MTILES, 256, 0, stream>>>(FX, Kh, Kl,
                                                 Y0, Y1, V0, V1, rq, bar, Xb, Mm);
  logits_kernel<<<15, 256, 0, stream>>>(Mm, Xb, gamma, out);
}

// Round 12
// 245.536 us; speedup vs baseline: 1.1783x; 1.1783x over previous
//
#include <hip/hip_runtime.h>
#include <math.h>

#define DIN 3072
#define DF 640
#define MROWS 400
#define QROWS 240
#define NMAT 400
#define PN 416          // padded A dim (13*32, 26*16)
#define NRHS 16
#define CREG 50.0f
#define PVSTEPS 5
#define CSTEPS 25       // Chebyshev: 2*q^25 ~ 3.5e-3 rel (q~0.78)
#define KSPLIT 4        // feat split-K factor
#define GBLK 13         // solve blocks; each owns 32 cols of A in LDS
#define SCOLS 32
#define SPAD 40         // solve LDS pad (R9-proven)
#define FPAD 72         // feat staging pad
#define MTILES 28       // M = FX@K^T: 4 row-tiles x 7 col-tiles of 64

typedef __attribute__((ext_vector_type(8))) short bf8v;   // 8 bf16 (4 VGPRs)
typedef __attribute__((ext_vector_type(4))) short s4v;    // 4 bf16 (8 B)
typedef __attribute__((ext_vector_type(4))) float f32x4;  // MFMA acc

__device__ __forceinline__ short bf16_rn(float x) {
  unsigned u = __float_as_uint(x);
  u += 0x7FFFu + ((u >> 16) & 1u);
  return (short)(u >> 16);
}
__device__ __forceinline__ void split_sh(float x, short& h, short& l) {
  h = bf16_rn(x);
  float hf = __uint_as_float(((unsigned)(unsigned short)h) << 16);
  l = bf16_rn(x - hf);
}
__device__ __forceinline__ float bf2f(short h) {
  return __uint_as_float(((unsigned)(unsigned short)h) << 16);
}

// ---- feat split-K: [S;Q](640x3072) @ Wb -> 4 partial slices (atomic-free) -
__global__ __launch_bounds__(256) void gemm_feat_sk(const float* __restrict__ S,
                                                    const float* __restrict__ Qm,
                                                    const float* __restrict__ Wb,
                                                    float* __restrict__ Acc) {
  __shared__ short Ash[64][FPAD];
  __shared__ short Asl[64][FPAD];
  __shared__ short Bsh[64][FPAD];
  __shared__ short Bsl[64][FPAD];
  int tid = threadIdx.x;
  int wave = tid >> 6, lane = tid & 63, l16 = lane & 15, quad = lane >> 4;
  int by = blockIdx.y, bx = blockIdx.x, bz = blockIdx.z;
  int colBase = bx * 64;
  int kbeg = bz * (DIN / KSPLIT), kend = kbeg + (DIN / KSPLIT);
  f32x4 acc[4] = {{0,0,0,0},{0,0,0,0},{0,0,0,0},{0,0,0,0}};
  for (int k0 = kbeg; k0 < kend; k0 += 64) {
    __syncthreads();
#pragma unroll
    for (int p = 0; p < 4; ++p) {
      int cid = tid + 256 * p;            // 0..1023
      int row = cid >> 4, kc4 = (cid & 15) * 4;
      int arow = by * 64 + row;
      const float* sr = (arow < MROWS) ? (S + (size_t)arow * DIN)
                                       : (Qm + (size_t)(arow - MROWS) * DIN);
      float4 v = *reinterpret_cast<const float4*>(sr + k0 + kc4);
      s4v hv, lv;
      short h, l;
      split_sh(v.x, h, l); hv[0] = h; lv[0] = l;
      split_sh(v.y, h, l); hv[1] = h; lv[1] = l;
      split_sh(v.z, h, l); hv[2] = h; lv[2] = l;
      split_sh(v.w, h, l); hv[3] = h; lv[3] = l;
      *reinterpret_cast<s4v*>(&Ash[row][kc4]) = hv;
      *reinterpret_cast<s4v*>(&Asl[row][kc4]) = lv;
    }
#pragma unroll
    for (int p = 0; p < 4; ++p) {
      int cid = tid + 256 * p;
      int r = cid >> 4, c4 = (cid & 15) * 4;
      float4 w = *reinterpret_cast<const float4*>(Wb + (size_t)(k0 + r) * DF + colBase + c4);
      short h, l;
      split_sh(w.x, h, l); Bsh[c4 + 0][r] = h; Bsl[c4 + 0][r] = l;
      split_sh(w.y, h, l); Bsh[c4 + 1][r] = h; Bsl[c4 + 1][r] = l;
      split_sh(w.z, h, l); Bsh[c4 + 2][r] = h; Bsl[c4 + 2][r] = l;
      split_sh(w.w, h, l); Bsh[c4 + 3][r] = h; Bsl[c4 + 3][r] = l;
    }
    __syncthreads();
#pragma unroll
    for (int kk = 0; kk < 64; kk += 32) {
      int ko = kk + quad * 8;
      bf8v ah = *reinterpret_cast<const bf8v*>(&Ash[wave * 16 + l16][ko]);
      bf8v al = *reinterpret_cast<const bf8v*>(&Asl[wave * 16 + l16][ko]);
#pragma unroll
      for (int t = 0; t < 4; ++t) {
        bf8v bh = *reinterpret_cast<const bf8v*>(&Bsh[t * 16 + l16][ko]);
        bf8v bl = *reinterpret_cast<const bf8v*>(&Bsl[t * 16 + l16][ko]);
        acc[t] = __builtin_amdgcn_mfma_f32_16x16x32_bf16(ah, bh, acc[t], 0, 0, 0);
        acc[t] = __builtin_amdgcn_mfma_f32_16x16x32_bf16(ah, bl, acc[t], 0, 0, 0);
        acc[t] = __builtin_amdgcn_mfma_f32_16x16x32_bf16(al, bh, acc[t], 0, 0, 0);
      }
    }
  }
  float* Ap = Acc + (size_t)bz * 640 * DF;
  int row0 = by * 64 + wave * 16;
#pragma unroll
  for (int t = 0; t < 4; ++t)
#pragma unroll
    for (int r = 0; r < 4; ++r) {
      int row = row0 + quad * 4 + r;
      int col = colBase + t * 16 + l16;
      Ap[(size_t)row * DF + col] = acc[t][r];
    }
}

// ---- reduce 4 partial slices -> Kh/Kl (rows<400) / FX; block 0 zeroes ctrl
__global__ __launch_bounds__(256) void feat_reduce(const float* __restrict__ Acc,
                                                   short* __restrict__ Kh,
                                                   short* __restrict__ Kl,
                                                   float* __restrict__ FX,
                                                   float* __restrict__ zbuf) {
  int tid = threadIdx.x;
  if (blockIdx.x == 0) {
    for (int e = tid; e < 14160; e += 256) zbuf[e] = 0.f;
  }
  int idx = blockIdx.x * 256 + tid;   // < 640*640
  if (idx >= 640 * DF) return;
  float v = Acc[idx] + Acc[idx + 409600] + Acc[idx + 819200] + Acc[idx + 1228800];
  int row = idx / DF, col = idx - row * DF;
  if (row < MROWS) {
    short h, l; split_sh(v, h, l);
    Kh[(size_t)row * DF + col] = h;
    Kl[(size_t)row * DF + col] = l;
  } else {
    FX[(size_t)(row - MROWS) * DF + col] = v;
  }
}

// ---- MFMA: A(416x416) = K K^T + 50 I (zero-padded), bf16 hi/lo out --------
__global__ __launch_bounds__(256) void gemm_aul(const short* __restrict__ Kh,
                                                const short* __restrict__ Kl,
                                                short* __restrict__ Aph,
                                                short* __restrict__ Apl) {
  int tid = threadIdx.x;
  int wave = tid >> 6, lane = tid & 63;
  int l16 = lane & 15, quad = lane >> 4;
  int row0 = blockIdx.y * 64 + wave * 16;
  int colBase = blockIdx.x * 64;
  bool aValid = (row0 < MROWS);
  const bf8v bzero = {0,0,0,0,0,0,0,0};
  f32x4 acc[4] = {{0,0,0,0},{0,0,0,0},{0,0,0,0},{0,0,0,0}};
  for (int k0 = 0; k0 < DF; k0 += 32) {
    int ka = k0 + quad * 8;
    bf8v ah = bzero, al = bzero;
    if (aValid) {
      size_t ao = (size_t)(row0 + l16) * DF + ka;
      ah = *reinterpret_cast<const bf8v*>(Kh + ao);
      al = *reinterpret_cast<const bf8v*>(Kl + ao);
    }
#pragma unroll
    for (int t = 0; t < 4; ++t) {
      int colt = colBase + t * 16;
      bf8v bh = bzero, bl = bzero;
      if (colt < MROWS) {
        size_t bo = (size_t)(colt + l16) * DF + ka;
        bh = *reinterpret_cast<const bf8v*>(Kh + bo);
        bl = *reinterpret_cast<const bf8v*>(Kl + bo);
      }
      acc[t] = __builtin_amdgcn_mfma_f32_16x16x32_bf16(ah, bh, acc[t], 0, 0, 0);
      acc[t] = __builtin_amdgcn_mfma_f32_16x16x32_bf16(ah, bl, acc[t], 0, 0, 0);
      acc[t] = __builtin_amdgcn_mfma_f32_16x16x32_bf16(al, bh, acc[t], 0, 0, 0);
    }
  }
  if (row0 >= PN) return;
#pragma unroll
  for (int t = 0; t < 4; ++t) {
    int colt = colBase + t * 16;
    if (colt >= PN) continue;
#pragma unroll
    for (int r = 0; r < 4; ++r) {
      int row = row0 + quad * 4 + r;
      int col = colt + l16;
      float v = acc[t][r];
      if (row == col && row < MROWS) v += CREG;
      short h, l; split_sh(v, h, l);
      size_t o = (size_t)row * PN + col;
      Aph[o] = h; Apl[o] = l;
    }
  }
}

// ---- fused: blocks 0..12 = 32-column-split Chebyshev solve (R9 scheme);
//      blocks 13..40 = M = FX @ K^T (hides under the solve). -----------------
__global__ __launch_bounds__(256) void solve_and_m(const short* __restrict__ Aph,
                                                   const short* __restrict__ Apl,
                                                   const float* __restrict__ FX,
                                                   const short* __restrict__ Kh,
                                                   const short* __restrict__ Kl,
                                                   float* __restrict__ Y0,
                                                   float* __restrict__ Y1,
                                                   float* __restrict__ V0,
                                                   float* __restrict__ V1,
                                                   float* __restrict__ rq,
                                                   unsigned* __restrict__ bar,
                                                   float* __restrict__ X,
                                                   float* __restrict__ M) {
  int tid = threadIdx.x, b = blockIdx.x;
  int wave = tid >> 6, lane = tid & 63, l16 = lane & 15, quad = lane >> 4;
  const bf8v bzero = {0,0,0,0,0,0,0,0};

  if (b >= GBLK) {
    // ================= M role: tile of FX(240x640) @ K^T(640x400) =========
    int mt = b - GBLK;             // 0..27
    int mb = mt / 7, nb = mt - (mt / 7) * 7;
    int q0 = mb * 64 + wave * 16;
    f32x4 acc[4] = {{0,0,0,0},{0,0,0,0},{0,0,0,0},{0,0,0,0}};
    int arow = q0 + l16;
    bool aOk = (arow < QROWS);
    const float* fr = FX + (size_t)(aOk ? arow : 0) * DF;
    for (int k0 = 0; k0 < DF; k0 += 32) {
      int ka = k0 + quad * 8;
      bf8v ah = bzero, al = bzero;
      if (aOk) {
        float4 a0 = *reinterpret_cast<const float4*>(fr + ka);
        float4 a1 = *reinterpret_cast<const float4*>(fr + ka + 4);
        float av[8] = {a0.x, a0.y, a0.z, a0.w, a1.x, a1.y, a1.z, a1.w};
#pragma unroll
        for (int j = 0; j < 8; ++j) { short h, l; split_sh(av[j], h, l); ah[j] = h; al[j] = l; }
      }
#pragma unroll
      for (int t = 0; t < 4; ++t) {
        int n = nb * 64 + t * 16 + l16;
        bf8v bh = bzero, bl = bzero;
        if (n < NMAT) {
          bh = *reinterpret_cast<const bf8v*>(Kh + (size_t)n * DF + ka);
          bl = *reinterpret_cast<const bf8v*>(Kl + (size_t)n * DF + ka);
        }
        acc[t] = __builtin_amdgcn_mfma_f32_16x16x32_bf16(ah, bh, acc[t], 0, 0, 0);
        acc[t] = __builtin_amdgcn_mfma_f32_16x16x32_bf16(ah, bl, acc[t], 0, 0, 0);
        acc[t] = __builtin_amdgcn_mfma_f32_16x16x32_bf16(al, bh, acc[t], 0, 0, 0);
      }
    }
#pragma unroll
    for (int t = 0; t < 4; ++t)
#pragma unroll
      for (int r = 0; r < 4; ++r) {
        int row = q0 + quad * 4 + r;
        int col = nb * 64 + t * 16 + l16;
        if (row < QROWS && col < NMAT) M[(size_t)row * NMAT + col] = acc[t][r];
      }
    return;
  }

  // ================= solve role: 32-column slice (R9-proven) ===============
  __shared__ short AsT_h[PN][SPAD];   // AsT[i][jl] = A[r0+jl][i] (sym) 33.3KB
  __shared__ short AsT_l[PN][SPAD];   // 33.3KB
  __shared__ short dbT_h[16][SPAD];   // d B-operand [c][k_local]
  __shared__ short dbT_l[16][SPAD];
  __shared__ float pvp[SCOLS], pvc[SCOLS];
  __shared__ float scal[2];
  int r0 = b * SCOLS;

  for (int e = tid; e < SCOLS * (PN / 8); e += 256) {
    int jl = e / (PN / 8), ic = e - (e / (PN / 8)) * (PN / 8);
    bf8v vh = *reinterpret_cast<const bf8v*>(Aph + (size_t)(r0 + jl) * PN + ic * 8);
    bf8v vl = *reinterpret_cast<const bf8v*>(Apl + (size_t)(r0 + jl) * PN + ic * 8);
#pragma unroll
    for (int u = 0; u < 8; ++u) {
      AsT_h[ic * 8 + u][jl] = vh[u];
      AsT_l[ic * 8 + u][jl] = vl[u];
    }
  }
  for (int e = tid; e < 16 * SPAD; e += 256) {
    (&dbT_h[0][0])[e] = 0; (&dbT_l[0][0])[e] = 0;
  }
  __syncthreads();
  if (tid < SCOLS) {
    int gi = r0 + tid;
    float v = (gi < NMAT) ? (1.f + 0.125f * (float)(gi & 7)) : 0.f;
    pvc[tid] = v; pvp[tid] = 0.f;
    dbT_h[0][tid] = bf16_rn(v);
  }
  __syncthreads();

  unsigned ph = 0;
  auto gridbar = [&]() {
    __syncthreads();
    ++ph;
    if (tid == 0) {
      unsigned tgt = ph * GBLK;
      __hip_atomic_fetch_add(bar, 1u, __ATOMIC_RELEASE, __HIP_MEMORY_SCOPE_AGENT);
      while (__hip_atomic_load(bar, __ATOMIC_RELAXED, __HIP_MEMORY_SCOPE_AGENT) < tgt)
        __builtin_amdgcn_s_sleep(2);
    }
    __syncthreads();
  };

  // ---- power iteration: partial y = A[:,own] @ v_own, hi only, col 0 ----
  for (int s = 0; s < PVSTEPS; ++s) {
    float* Yv = (s & 1) ? V1 : V0;
    for (int t = wave; t < 26; t += 4) {
      f32x4 acc = {0, 0, 0, 0};
      bf8v bh = *reinterpret_cast<const bf8v*>(&dbT_h[l16][quad * 8]);
      bf8v ah = *reinterpret_cast<const bf8v*>(&AsT_h[t * 16 + l16][quad * 8]);
      acc = __builtin_amdgcn_mfma_f32_16x16x32_bf16(ah, bh, acc, 0, 0, 0);
      if (l16 == 0) {
#pragma unroll
        for (int r_ = 0; r_ < 4; ++r_)
          atomicAdd(&Yv[t * 16 + quad * 4 + r_], acc[r_]);
      }
    }
    gridbar();
    if (tid < SCOLS) {
      float y = atomicExch(&Yv[r0 + tid], 0.f);   // coherent read + re-zero
      float v = y * (1.f / 4096.f);
      pvp[tid] = pvc[tid];
      pvc[tid] = v;
      dbT_h[0][tid] = bf16_rn(v);
    }
    __syncthreads();
  }
  // ---- Rayleigh quotient (partial dots over own slice) ----
  if (tid == 0) {
    float n = 0.f, dd = 0.f;
    for (int u = 0; u < SCOLS; ++u) { n += pvp[u] * pvc[u]; dd += pvp[u] * pvp[u]; }
    atomicAdd(&rq[0], n);
    atomicAdd(&rq[1], dd);
  }
  gridbar();
  if (tid == 0) {
    float rn = atomicAdd(&rq[0], 0.f), rd = atomicAdd(&rq[1], 0.f);
    float rqv = 4096.f * rn / rd;
    float bb = 1.3f * rqv;
    if (!(bb > 800.f)) bb = 12000.f;   // degenerate/NaN fallback
    if (bb > 100000.f) bb = 100000.f;
    scal[0] = 0.5f * (bb + CREG);      // theta
    scal[1] = 0.5f * (bb - CREG);      // delta
  }
  __syncthreads();
  float theta = scal[0], delta = scal[1];
  float sigma = theta / delta, rho = 1.f / sigma;

  // ---- Chebyshev init: thread owns 2 (rl, c) pairs; overwrites PV d ----
  float xr[2], rr[2], dr[2];
#pragma unroll
  for (int m = 0; m < 2; ++m) {
    int rl = (tid >> 4) + 16 * m, c = tid & 15, gi = r0 + rl;
    float pc = (gi < NMAT && (gi / 25) == c) ? 1.f : 0.f;
    xr[m] = 0.f; rr[m] = pc; dr[m] = pc / theta;
    short h, l; split_sh(dr[m], h, l);
    dbT_h[c][rl] = h; dbT_l[c][rl] = l;
  }
  __syncthreads();

  // ---- Chebyshev steps (Saad Alg 12.1); CSTEPS-1 matvecs + final add ----
  for (int k = 0; k < CSTEPS - 1; ++k) {
    float* Yv = (k & 1) ? Y1 : Y0;
    for (int t = wave; t < 26; t += 4) {
      f32x4 acc = {0, 0, 0, 0};
      bf8v bh = *reinterpret_cast<const bf8v*>(&dbT_h[l16][quad * 8]);
      bf8v bl = *reinterpret_cast<const bf8v*>(&dbT_l[l16][quad * 8]);
      bf8v ah = *reinterpret_cast<const bf8v*>(&AsT_h[t * 16 + l16][quad * 8]);
      bf8v al = *reinterpret_cast<const bf8v*>(&AsT_l[t * 16 + l16][quad * 8]);
      acc = __builtin_amdgcn_mfma_f32_16x16x32_bf16(ah, bh, acc, 0, 0, 0);
      acc = __builtin_amdgcn_mfma_f32_16x16x32_bf16(ah, bl, acc, 0, 0, 0);
      acc = __builtin_amdgcn_mfma_f32_16x16x32_bf16(al, bh, acc, 0, 0, 0);
#pragma unroll
      for (int r_ = 0; r_ < 4; ++r_)
        atomicAdd(&Yv[(t * 16 + quad * 4 + r_) * 16 + l16], acc[r_]);
    }
    gridbar();
    float rho1 = 1.f / (2.f * sigma - rho);
    float s1 = rho1 * rho, s2 = 2.f * rho1 / delta;
    rho = rho1;
#pragma unroll
    for (int m = 0; m < 2; ++m) {
      int rl = (tid >> 4) + 16 * m, c = tid & 15, gi = r0 + rl;
      float mv = atomicExch(&Yv[gi * 16 + c], 0.f);   // read + re-zero
      xr[m] += dr[m];
      rr[m] -= mv;
      float dn = s1 * dr[m] + s2 * rr[m];
      dr[m] = dn;
      short h, l; split_sh(dn, h, l);
      dbT_h[c][rl] = h; dbT_l[c][rl] = l;
    }
    __syncthreads();
  }
#pragma unroll
  for (int m = 0; m < 2; ++m) {
    int rl = (tid >> 4) + 16 * m, c = tid & 15, gi = r0 + rl;
    if (gi < NMAT) X[gi * NRHS + c] = xr[m] + dr[m];
  }
}

// ---- logits[q][c] = -gamma * sum_i M[q][i] X[i][c]  (tiny, 240x400x16) ----
__global__ __launch_bounds__(256) void logits_kernel(const float* __restrict__ M,
                                                     const float* __restrict__ X,
                                                     const float* __restrict__ gamma,
                                                     float* __restrict__ out) {
  __shared__ float Xs[NMAT * NRHS];     // 25.6 KB
  __shared__ float Ms[16][NMAT];        // 25.6 KB
  int tid = threadIdx.x;
  int q0 = blockIdx.x * 16;
  for (int e = tid; e < NMAT * NRHS; e += 256) Xs[e] = X[e];
  for (int e = tid; e < 16 * NMAT; e += 256) {
    int rl = e / NMAT, i = e - (e / NMAT) * NMAT;
    Ms[rl][i] = M[(size_t)(q0 + rl) * NMAT + i];
  }
  __syncthreads();
  int ql = tid >> 4, c = tid & 15;
  float acc = 0.f;
  for (int i = 0; i < NMAT; ++i) acc += Ms[ql][i] * Xs[i * NRHS + c];
  out[(size_t)(q0 + ql) * NRHS + c] = -gamma[0] * acc;
}

extern "C" void kernel_launch(void* const* d_in, const int* in_sizes, int n_in,
                              void* d_out, int out_size, void* d_ws, size_t ws_size,
                              hipStream_t stream) {
  const float* S = (const float*)d_in[0];
  const float* Qm = (const float*)d_in[1];
  const float* Wb = (const float*)d_in[2];
  const float* gamma = (const float*)d_in[3];
  float* out = (float*)d_out;
  char* base = (char*)d_ws;
  short* Kh   = (short*)(base);                  // 400*640*2 = 512,000
  short* Kl   = (short*)(base + 512000);         // 512,000
  float* FX   = (float*)(base + 1024000);        // 240*640*4 = 614,400
  short* Aph  = (short*)(base + 1638400);        // 416*416*2 = 346,112
  short* Apl  = (short*)(base + 1984512);        // 346,112
  float* Mm   = (float*)(base + 2330624);        // 240*400*4 = 384,000
  float* Xb   = (float*)(base + 2714624);        // 25,600
  unsigned* bar = (unsigned*)(base + 2740224);   // ctrl (64 B): bar, rq
  float* rq   = (float*)(base + 2740232);
  float* zbuf = (float*)(base + 2740224);        // zero region: ctrl..V1 (14160 f)
  float* Y0   = (float*)(base + 2740288);        // 26,624
  float* Y1   = (float*)(base + 2766912);        // 26,624
  float* V0   = (float*)(base + 2793536);        // 1,664
  float* V1   = (float*)(base + 2795200);        // 1,664 -> end 2,796,864
  float* Acc  = (float*)(base + 2796864);        // 4*640*640*4 = 6,553,600
                                                 // -> total 9,350,464 B

  gemm_feat_sk<<<dim3(10, 10, KSPLIT), 256, 0, stream>>>(S, Qm, Wb, Acc);
  feat_reduce<<<1600, 256, 0, stream>>>(Acc, Kh, Kl, FX, zbuf);
  gemm_aul<<<dim3(7, 7), 256, 0, stream>>>(Kh, Kl, Aph, Apl);
  solve_and_m<<<GBLK + MTILES, 256, 0, stream>>>(Aph, Apl, FX, Kh, Kl,
                                                 Y0, Y1, V0, V1, rq, bar, Xb, Mm);
  logits_kernel<<<15, 256, 0, stream>>>(Mm, Xb, gamma, out);
}

// Round 13
// 229.236 us; speedup vs baseline: 1.2621x; 1.0711x over previous
//
#include <hip/hip_runtime.h>
#include <math.h>

#define DIN 3072
#define DF 640
#define MROWS 400
#define QROWS 240
#define NMAT 400
#define PN 416          // padded A dim (13*32, 26*16)
#define NRHS 16
#define CREG 50.0f
#define PVSTEPS 5
#define CSTEPS 25       // Chebyshev: 2*q^25 ~ 3.5e-3 rel (q~0.78)
#define KSPLIT 4        // feat split-K factor
#define GBLK 13         // solve blocks; each owns 32 cols of A in LDS
#define SCOLS 32
#define SPAD 40         // solve LDS pad (R9-proven)
#define FPAD 72         // feat staging pad
#define MTILES 28       // M = FX@K^T: 4 row-tiles x 7 col-tiles of 64

typedef __attribute__((ext_vector_type(8))) short bf8v;   // 8 bf16 (4 VGPRs)
typedef __attribute__((ext_vector_type(4))) short s4v;    // 4 bf16 (8 B)
typedef __attribute__((ext_vector_type(4))) float f32x4;  // MFMA acc

__device__ __forceinline__ short bf16_rn(float x) {
  unsigned u = __float_as_uint(x);
  u += 0x7FFFu + ((u >> 16) & 1u);
  return (short)(u >> 16);
}
__device__ __forceinline__ void split_sh(float x, short& h, short& l) {
  h = bf16_rn(x);
  float hf = __uint_as_float(((unsigned)(unsigned short)h) << 16);
  l = bf16_rn(x - hf);
}
__device__ __forceinline__ float bf2f(short h) {
  return __uint_as_float(((unsigned)(unsigned short)h) << 16);
}

// ---- feat split-K: [S;Q](640x3072) @ Wb -> 4 partial slices (atomic-free) -
// Double-buffered: next tile's global loads prefetched into regs before MFMA.
__global__ __launch_bounds__(256) void gemm_feat_sk(const float* __restrict__ S,
                                                    const float* __restrict__ Qm,
                                                    const float* __restrict__ Wb,
                                                    float* __restrict__ Acc) {
  __shared__ short Ash[64][FPAD];
  __shared__ short Asl[64][FPAD];
  __shared__ short Bsh[64][FPAD];
  __shared__ short Bsl[64][FPAD];
  int tid = threadIdx.x;
  int wave = tid >> 6, lane = tid & 63, l16 = lane & 15, quad = lane >> 4;
  int by = blockIdx.y, bx = blockIdx.x, bz = blockIdx.z;
  int colBase = bx * 64;
  int kbeg = bz * (DIN / KSPLIT), kend = kbeg + (DIN / KSPLIT);
  // per-thread staging addresses (fixed across iters except k offset)
  int arow = by * 64 + (tid >> 4);
  const float* sr = (arow < MROWS) ? (S + (size_t)arow * DIN)
                                   : (Qm + (size_t)(arow - MROWS) * DIN);
  int kc4 = (tid & 15) * 4;
  float4 ar4[4], br4[4];
  auto load_regs = [&](int kk) {
#pragma unroll
    for (int p = 0; p < 4; ++p) {
      // A: rows arow + 16p (same row-group stride pattern as before)
      int rowoff = 16 * p;     // cid = tid + 256p -> row = (tid>>4) + 16p
      const float* srp;
      {
        int ar_ = by * 64 + (tid >> 4) + rowoff;
        srp = (ar_ < MROWS) ? (S + (size_t)ar_ * DIN) : (Qm + (size_t)(ar_ - MROWS) * DIN);
      }
      ar4[p] = *reinterpret_cast<const float4*>(srp + kk + kc4);
      int r = (tid >> 4) + rowoff;
      br4[p] = *reinterpret_cast<const float4*>(Wb + (size_t)(kk + r) * DF + colBase + kc4);
    }
  };
  auto split_write = [&]() {
#pragma unroll
    for (int p = 0; p < 4; ++p) {
      int row = (tid >> 4) + 16 * p;
      s4v hv, lv; short h, l;
      split_sh(ar4[p].x, h, l); hv[0] = h; lv[0] = l;
      split_sh(ar4[p].y, h, l); hv[1] = h; lv[1] = l;
      split_sh(ar4[p].z, h, l); hv[2] = h; lv[2] = l;
      split_sh(ar4[p].w, h, l); hv[3] = h; lv[3] = l;
      *reinterpret_cast<s4v*>(&Ash[row][kc4]) = hv;
      *reinterpret_cast<s4v*>(&Asl[row][kc4]) = lv;
      split_sh(br4[p].x, h, l); Bsh[kc4 + 0][row] = h; Bsl[kc4 + 0][row] = l;
      split_sh(br4[p].y, h, l); Bsh[kc4 + 1][row] = h; Bsl[kc4 + 1][row] = l;
      split_sh(br4[p].z, h, l); Bsh[kc4 + 2][row] = h; Bsl[kc4 + 2][row] = l;
      split_sh(br4[p].w, h, l); Bsh[kc4 + 3][row] = h; Bsl[kc4 + 3][row] = l;
    }
  };
  f32x4 acc[4] = {{0,0,0,0},{0,0,0,0},{0,0,0,0},{0,0,0,0}};
  load_regs(kbeg);
  split_write();
  __syncthreads();
  int k0 = kbeg;
  while (true) {
    int kn = k0 + 64;
    bool more = (kn < kend);
    if (more) load_regs(kn);            // prefetch overlaps MFMA below
#pragma unroll
    for (int kk = 0; kk < 64; kk += 32) {
      int ko = kk + quad * 8;
      bf8v ah = *reinterpret_cast<const bf8v*>(&Ash[wave * 16 + l16][ko]);
      bf8v al = *reinterpret_cast<const bf8v*>(&Asl[wave * 16 + l16][ko]);
#pragma unroll
      for (int t = 0; t < 4; ++t) {
        bf8v bh = *reinterpret_cast<const bf8v*>(&Bsh[t * 16 + l16][ko]);
        bf8v bl = *reinterpret_cast<const bf8v*>(&Bsl[t * 16 + l16][ko]);
        acc[t] = __builtin_amdgcn_mfma_f32_16x16x32_bf16(ah, bh, acc[t], 0, 0, 0);
        acc[t] = __builtin_amdgcn_mfma_f32_16x16x32_bf16(ah, bl, acc[t], 0, 0, 0);
        acc[t] = __builtin_amdgcn_mfma_f32_16x16x32_bf16(al, bh, acc[t], 0, 0, 0);
      }
    }
    if (!more) break;
    __syncthreads();                    // all waves done reading LDS
    split_write();                      // waits on prefetch, splits, stores
    __syncthreads();
    k0 = kn;
  }
  float* Ap = Acc + (size_t)bz * 640 * DF;
  int row0 = by * 64 + wave * 16;
#pragma unroll
  for (int t = 0; t < 4; ++t)
#pragma unroll
    for (int r = 0; r < 4; ++r) {
      int row = row0 + quad * 4 + r;
      int col = colBase + t * 16 + l16;
      Ap[(size_t)row * DF + col] = acc[t][r];
    }
}

// ---- reduce 4 partial slices -> Kh/Kl / FX; blk0 zeroes ctrl, blk1 zeroes out
__global__ __launch_bounds__(256) void feat_reduce(const float* __restrict__ Acc,
                                                   short* __restrict__ Kh,
                                                   short* __restrict__ Kl,
                                                   float* __restrict__ FX,
                                                   float* __restrict__ zbuf,
                                                   float* __restrict__ out) {
  int tid = threadIdx.x;
  if (blockIdx.x == 0) {
    for (int e = tid; e < 14160; e += 256) zbuf[e] = 0.f;
  } else if (blockIdx.x == 1) {
    for (int e = tid; e < QROWS * NRHS; e += 256) out[e] = 0.f;
  }
  int idx = blockIdx.x * 256 + tid;   // < 640*640
  if (idx >= 640 * DF) return;
  float v = Acc[idx] + Acc[idx + 409600] + Acc[idx + 819200] + Acc[idx + 1228800];
  int row = idx / DF, col = idx - row * DF;
  if (row < MROWS) {
    short h, l; split_sh(v, h, l);
    Kh[(size_t)row * DF + col] = h;
    Kl[(size_t)row * DF + col] = l;
  } else {
    FX[(size_t)(row - MROWS) * DF + col] = v;
  }
}

// ---- MFMA: A(416x416) = K K^T + 50 I (zero-padded), bf16 hi/lo out --------
__global__ __launch_bounds__(256) void gemm_aul(const short* __restrict__ Kh,
                                                const short* __restrict__ Kl,
                                                short* __restrict__ Aph,
                                                short* __restrict__ Apl) {
  int tid = threadIdx.x;
  int wave = tid >> 6, lane = tid & 63;
  int l16 = lane & 15, quad = lane >> 4;
  int row0 = blockIdx.y * 64 + wave * 16;
  int colBase = blockIdx.x * 64;
  bool aValid = (row0 < MROWS);
  const bf8v bzero = {0,0,0,0,0,0,0,0};
  f32x4 acc[4] = {{0,0,0,0},{0,0,0,0},{0,0,0,0},{0,0,0,0}};
  for (int k0 = 0; k0 < DF; k0 += 32) {
    int ka = k0 + quad * 8;
    bf8v ah = bzero, al = bzero;
    if (aValid) {
      size_t ao = (size_t)(row0 + l16) * DF + ka;
      ah = *reinterpret_cast<const bf8v*>(Kh + ao);
      al = *reinterpret_cast<const bf8v*>(Kl + ao);
    }
#pragma unroll
    for (int t = 0; t < 4; ++t) {
      int colt = colBase + t * 16;
      bf8v bh = bzero, bl = bzero;
      if (colt < MROWS) {
        size_t bo = (size_t)(colt + l16) * DF + ka;
        bh = *reinterpret_cast<const bf8v*>(Kh + bo);
        bl = *reinterpret_cast<const bf8v*>(Kl + bo);
      }
      acc[t] = __builtin_amdgcn_mfma_f32_16x16x32_bf16(ah, bh, acc[t], 0, 0, 0);
      acc[t] = __builtin_amdgcn_mfma_f32_16x16x32_bf16(ah, bl, acc[t], 0, 0, 0);
      acc[t] = __builtin_amdgcn_mfma_f32_16x16x32_bf16(al, bh, acc[t], 0, 0, 0);
    }
  }
  if (row0 >= PN) return;
#pragma unroll
  for (int t = 0; t < 4; ++t) {
    int colt = colBase + t * 16;
    if (colt >= PN) continue;
#pragma unroll
    for (int r = 0; r < 4; ++r) {
      int row = row0 + quad * 4 + r;
      int col = colt + l16;
      float v = acc[t][r];
      if (row == col && row < MROWS) v += CREG;
      short h, l; split_sh(v, h, l);
      size_t o = (size_t)row * PN + col;
      Aph[o] = h; Apl[o] = l;
    }
  }
}

// ---- fused: blocks 0..12 = 32-col-split Chebyshev solve + logits epilogue;
//      blocks 13..40 = M = FX @ K^T (atomic stores + release flag). ---------
__global__ __launch_bounds__(256) void solve_and_m(const short* __restrict__ Aph,
                                                   const short* __restrict__ Apl,
                                                   const float* __restrict__ FX,
                                                   const short* __restrict__ Kh,
                                                   const short* __restrict__ Kl,
                                                   const float* __restrict__ gamma,
                                                   float* __restrict__ Y0,
                                                   float* __restrict__ Y1,
                                                   float* __restrict__ V0,
                                                   float* __restrict__ V1,
                                                   float* __restrict__ rq,
                                                   unsigned* __restrict__ bar,
                                                   unsigned* __restrict__ mflag,
                                                   float* __restrict__ M,
                                                   float* __restrict__ out) {
  int tid = threadIdx.x, b = blockIdx.x;
  int wave = tid >> 6, lane = tid & 63, l16 = lane & 15, quad = lane >> 4;
  const bf8v bzero = {0,0,0,0,0,0,0,0};

  if (b >= GBLK) {
    // ================= M role: tile of FX(240x640) @ K^T(640x400) =========
    int mt = b - GBLK;             // 0..27
    int mb = mt / 7, nb = mt - (mt / 7) * 7;
    int q0 = mb * 64 + wave * 16;
    f32x4 acc[4] = {{0,0,0,0},{0,0,0,0},{0,0,0,0},{0,0,0,0}};
    int arow = q0 + l16;
    bool aOk = (arow < QROWS);
    const float* fr = FX + (size_t)(aOk ? arow : 0) * DF;
    for (int k0 = 0; k0 < DF; k0 += 32) {
      int ka = k0 + quad * 8;
      bf8v ah = bzero, al = bzero;
      if (aOk) {
        float4 a0 = *reinterpret_cast<const float4*>(fr + ka);
        float4 a1 = *reinterpret_cast<const float4*>(fr + ka + 4);
        float av[8] = {a0.x, a0.y, a0.z, a0.w, a1.x, a1.y, a1.z, a1.w};
#pragma unroll
        for (int j = 0; j < 8; ++j) { short h, l; split_sh(av[j], h, l); ah[j] = h; al[j] = l; }
      }
#pragma unroll
      for (int t = 0; t < 4; ++t) {
        int n = nb * 64 + t * 16 + l16;
        bf8v bh = bzero, bl = bzero;
        if (n < NMAT) {
          bh = *reinterpret_cast<const bf8v*>(Kh + (size_t)n * DF + ka);
          bl = *reinterpret_cast<const bf8v*>(Kl + (size_t)n * DF + ka);
        }
        acc[t] = __builtin_amdgcn_mfma_f32_16x16x32_bf16(ah, bh, acc[t], 0, 0, 0);
        acc[t] = __builtin_amdgcn_mfma_f32_16x16x32_bf16(ah, bl, acc[t], 0, 0, 0);
        acc[t] = __builtin_amdgcn_mfma_f32_16x16x32_bf16(al, bh, acc[t], 0, 0, 0);
      }
    }
#pragma unroll
    for (int t = 0; t < 4; ++t)
#pragma unroll
      for (int r = 0; r < 4; ++r) {
        int row = q0 + quad * 4 + r;
        int col = nb * 64 + t * 16 + l16;
        if (row < QROWS && col < NMAT)
          __hip_atomic_store(&M[(size_t)row * NMAT + col], acc[t][r],
                             __ATOMIC_RELAXED, __HIP_MEMORY_SCOPE_AGENT);
      }
    __syncthreads();
    if (tid == 0)
      __hip_atomic_fetch_add(mflag, 1u, __ATOMIC_RELEASE, __HIP_MEMORY_SCOPE_AGENT);
    return;
  }

  // ================= solve role: 32-column slice (R9-proven) ===============
  __shared__ __align__(16) short AsT_h[PN][SPAD];   // 33.3KB (reused for M slice)
  __shared__ short AsT_l[PN][SPAD];   // 33.3KB
  __shared__ short dbT_h[16][SPAD];
  __shared__ short dbT_l[16][SPAD];
  __shared__ float pvp[SCOLS], pvc[SCOLS];
  __shared__ float scal[2];
  __shared__ float XsL[SCOLS][NRHS + 1];   // own X slice for epilogue, 2.2KB
  int r0 = b * SCOLS;

  for (int e = tid; e < SCOLS * (PN / 8); e += 256) {
    int jl = e / (PN / 8), ic = e - (e / (PN / 8)) * (PN / 8);
    bf8v vh = *reinterpret_cast<const bf8v*>(Aph + (size_t)(r0 + jl) * PN + ic * 8);
    bf8v vl = *reinterpret_cast<const bf8v*>(Apl + (size_t)(r0 + jl) * PN + ic * 8);
#pragma unroll
    for (int u = 0; u < 8; ++u) {
      AsT_h[ic * 8 + u][jl] = vh[u];
      AsT_l[ic * 8 + u][jl] = vl[u];
    }
  }
  for (int e = tid; e < 16 * SPAD; e += 256) {
    (&dbT_h[0][0])[e] = 0; (&dbT_l[0][0])[e] = 0;
  }
  __syncthreads();
  if (tid < SCOLS) {
    int gi = r0 + tid;
    float v = (gi < NMAT) ? (1.f + 0.125f * (float)(gi & 7)) : 0.f;
    pvc[tid] = v; pvp[tid] = 0.f;
    dbT_h[0][tid] = bf16_rn(v);
  }
  __syncthreads();

  unsigned ph = 0;
  auto gridbar = [&]() {
    __syncthreads();
    ++ph;
    if (tid == 0) {
      unsigned tgt = ph * GBLK;
      __hip_atomic_fetch_add(bar, 1u, __ATOMIC_RELEASE, __HIP_MEMORY_SCOPE_AGENT);
      while (__hip_atomic_load(bar, __ATOMIC_RELAXED, __HIP_MEMORY_SCOPE_AGENT) < tgt)
        __builtin_amdgcn_s_sleep(2);
    }
    __syncthreads();
  };

  // ---- power iteration: partial y = A[:,own] @ v_own, hi only, col 0 ----
  for (int s = 0; s < PVSTEPS; ++s) {
    float* Yv = (s & 1) ? V1 : V0;
    for (int t = wave; t < 26; t += 4) {
      f32x4 acc = {0, 0, 0, 0};
      bf8v bh = *reinterpret_cast<const bf8v*>(&dbT_h[l16][quad * 8]);
      bf8v ah = *reinterpret_cast<const bf8v*>(&AsT_h[t * 16 + l16][quad * 8]);
      acc = __builtin_amdgcn_mfma_f32_16x16x32_bf16(ah, bh, acc, 0, 0, 0);
      if (l16 == 0) {
#pragma unroll
        for (int r_ = 0; r_ < 4; ++r_)
          atomicAdd(&Yv[t * 16 + quad * 4 + r_], acc[r_]);
      }
    }
    gridbar();
    if (tid < SCOLS) {
      float y = atomicExch(&Yv[r0 + tid], 0.f);   // coherent read + re-zero
      float v = y * (1.f / 4096.f);
      pvp[tid] = pvc[tid];
      pvc[tid] = v;
      dbT_h[0][tid] = bf16_rn(v);
    }
    __syncthreads();
  }
  // ---- Rayleigh quotient (partial dots over own slice) ----
  if (tid == 0) {
    float n = 0.f, dd = 0.f;
    for (int u = 0; u < SCOLS; ++u) { n += pvp[u] * pvc[u]; dd += pvp[u] * pvp[u]; }
    atomicAdd(&rq[0], n);
    atomicAdd(&rq[1], dd);
  }
  gridbar();
  if (tid == 0) {
    float rn = atomicAdd(&rq[0], 0.f), rd = atomicAdd(&rq[1], 0.f);
    float rqv = 4096.f * rn / rd;
    float bb = 1.3f * rqv;
    if (!(bb > 800.f)) bb = 12000.f;   // degenerate/NaN fallback
    if (bb > 100000.f) bb = 100000.f;
    scal[0] = 0.5f * (bb + CREG);      // theta
    scal[1] = 0.5f * (bb - CREG);      // delta
  }
  __syncthreads();
  float theta = scal[0], delta = scal[1];
  float sigma = theta / delta, rho = 1.f / sigma;

  // ---- Chebyshev init: thread owns 2 (rl, c) pairs; overwrites PV d ----
  float xr[2], rr[2], dr[2];
#pragma unroll
  for (int m = 0; m < 2; ++m) {
    int rl = (tid >> 4) + 16 * m, c = tid & 15, gi = r0 + rl;
    float pc = (gi < NMAT && (gi / 25) == c) ? 1.f : 0.f;
    xr[m] = 0.f; rr[m] = pc; dr[m] = pc / theta;
    short h, l; split_sh(dr[m], h, l);
    dbT_h[c][rl] = h; dbT_l[c][rl] = l;
  }
  __syncthreads();

  // ---- Chebyshev steps (Saad Alg 12.1); CSTEPS-1 matvecs + final add ----
  for (int k = 0; k < CSTEPS - 1; ++k) {
    float* Yv = (k & 1) ? Y1 : Y0;
    for (int t = wave; t < 26; t += 4) {
      f32x4 acc = {0, 0, 0, 0};
      bf8v bh = *reinterpret_cast<const bf8v*>(&dbT_h[l16][quad * 8]);
      bf8v bl = *reinterpret_cast<const bf8v*>(&dbT_l[l16][quad * 8]);
      bf8v ah = *reinterpret_cast<const bf8v*>(&AsT_h[t * 16 + l16][quad * 8]);
      bf8v al = *reinterpret_cast<const bf8v*>(&AsT_l[t * 16 + l16][quad * 8]);
      acc = __builtin_amdgcn_mfma_f32_16x16x32_bf16(ah, bh, acc, 0, 0, 0);
      acc = __builtin_amdgcn_mfma_f32_16x16x32_bf16(ah, bl, acc, 0, 0, 0);
      acc = __builtin_amdgcn_mfma_f32_16x16x32_bf16(al, bh, acc, 0, 0, 0);
#pragma unroll
      for (int r_ = 0; r_ < 4; ++r_)
        atomicAdd(&Yv[(t * 16 + quad * 4 + r_) * 16 + l16], acc[r_]);
    }
    gridbar();
    float rho1 = 1.f / (2.f * sigma - rho);
    float s1 = rho1 * rho, s2 = 2.f * rho1 / delta;
    rho = rho1;
#pragma unroll
    for (int m = 0; m < 2; ++m) {
      int rl = (tid >> 4) + 16 * m, c = tid & 15, gi = r0 + rl;
      float mv = atomicExch(&Yv[gi * 16 + c], 0.f);   // read + re-zero
      xr[m] += dr[m];
      rr[m] -= mv;
      float dn = s1 * dr[m] + s2 * rr[m];
      dr[m] = dn;
      short h, l; split_sh(dn, h, l);
      dbT_h[c][rl] = h; dbT_l[c][rl] = l;
    }
    __syncthreads();
  }
  // ---- fused logits epilogue: out[q][c] += -gamma * M[q, own] . X[own, c] --
#pragma unroll
  for (int m = 0; m < 2; ++m) {
    int rl = (tid >> 4) + 16 * m, c = tid & 15;
    XsL[rl][c] = xr[m] + dr[m];
  }
  __syncthreads();
  if (tid == 0) {
    while (__hip_atomic_load(mflag, __ATOMIC_RELAXED, __HIP_MEMORY_SCOPE_AGENT) < MTILES)
      __builtin_amdgcn_s_sleep(2);
  }
  __syncthreads();
  float* Msl = reinterpret_cast<float*>(&AsT_h[0][0]);   // 240*32*4 = 30.7KB <= 33.3KB
  for (int e = tid; e < QROWS * SCOLS; e += 256) {
    int q = e >> 5, i = e & 31;
    float v = 0.f;
    if (r0 + i < NMAT)
      v = __hip_atomic_load(&M[(size_t)q * NMAT + r0 + i],
                            __ATOMIC_RELAXED, __HIP_MEMORY_SCOPE_AGENT);
    Msl[e] = v;
  }
  __syncthreads();
  float g = -gamma[0];
  int c = tid & 15;
  for (int q = tid >> 4; q < QROWS; q += 16) {
    float s = 0.f;
#pragma unroll
    for (int i = 0; i < SCOLS; ++i) s += Msl[q * SCOLS + i] * XsL[i][c];
    atomicAdd(&out[q * NRHS + c], g * s);
  }
}

extern "C" void kernel_launch(void* const* d_in, const int* in_sizes, int n_in,
                              void* d_out, int out_size, void* d_ws, size_t ws_size,
                              hipStream_t stream) {
  const float* S = (const float*)d_in[0];
  const float* Qm = (const float*)d_in[1];
  const float* Wb = (const float*)d_in[2];
  const float* gamma = (const float*)d_in[3];
  float* out = (float*)d_out;
  char* base = (char*)d_ws;
  short* Kh   = (short*)(base);                  // 400*640*2 = 512,000
  short* Kl   = (short*)(base + 512000);         // 512,000
  float* FX   = (float*)(base + 1024000);        // 240*640*4 = 614,400
  short* Aph  = (short*)(base + 1638400);        // 416*416*2 = 346,112
  short* Apl  = (short*)(base + 1984512);        // 346,112
  float* Mm   = (float*)(base + 2330624);        // 240*400*4 = 384,000
  unsigned* bar = (unsigned*)(base + 2740224);   // ctrl (64 B): bar, rq, mflag
  float* rq   = (float*)(base + 2740232);
  unsigned* mflag = (unsigned*)(base + 2740240);
  float* zbuf = (float*)(base + 2740224);        // zero region: ctrl..V1 (14160 f)
  float* Y0   = (float*)(base + 2740288);        // 26,624
  float* Y1   = (float*)(base + 2766912);        // 26,624
  float* V0   = (float*)(base + 2793536);        // 1,664
  float* V1   = (float*)(base + 2795200);        // 1,664 -> end 2,796,864
  float* Acc  = (float*)(base + 2796864);        // 4*640*640*4 = 6,553,600
                                                 // -> total 9,350,464 B

  gemm_feat_sk<<<dim3(10, 10, KSPLIT), 256, 0, stream>>>(S, Qm, Wb, Acc);
  feat_reduce<<<1600, 256, 0, stream>>>(Acc, Kh, Kl, FX, zbuf, out);
  gemm_aul<<<dim3(7, 7), 256, 0, stream>>>(Kh, Kl, Aph, Apl);
  solve_and_m<<<GBLK + MTILES, 256, 0, stream>>>(Aph, Apl, FX, Kh, Kl, gamma,
                                                 Y0, Y1, V0, V1, rq, bar, mflag,
                                                 Mm, out);
}